// Round 20
// baseline (875.786 us; speedup 1.0000x reference)
//
#include <hip/hip_runtime.h>
#include <math.h>

typedef __attribute__((ext_vector_type(8))) short short8;
typedef __attribute__((ext_vector_type(4))) short short4v;
typedef __attribute__((ext_vector_type(4))) float f32x4;

union U32S8 { unsigned u[4]; short8 s8; ushort e[8]; short4v h[2]; };

#define BATCH 128
#define NHIS  50
#define NCAND 5
#define KP    320    // padded K stride (elems) for weights, emb_bf, news_enc_bf
#define NQKV  1024   // padded N for [Wq|Wk|Wv] weight buffer (8 exact 128-panels)
#define NWP   208    // padded N for Wp
#define NQK   640    // Q|K row width (1280B rows, 128B-aligned)
#define CTS   320    // user ctx row stride
#define VOCAB 60000
#define SCALE 0.22360679774997896f  // 1/sqrt(20)

__device__ __forceinline__ ushort f2bf(float f) {
    union { float f; unsigned u; } v; v.f = f;
    return (ushort)((v.u + 0x7fffu + ((v.u >> 16) & 1u)) >> 16);
}
__device__ __forceinline__ unsigned pack2bf(float lo, float hi) {
    return (unsigned)f2bf(lo) | ((unsigned)f2bf(hi) << 16);
}
__device__ __forceinline__ float bf2f(ushort u) {
    union { float f; unsigned u; } v; v.u = ((unsigned)u) << 16;
    return v.f;
}

// async global -> LDS, 16B per lane (dest = wave-uniform base + lane*16)
__device__ __forceinline__ void gl_lds16(const ushort* gsrc, ushort* ldst) {
    __builtin_amdgcn_global_load_lds(
        (const __attribute__((address_space(1))) unsigned int*)gsrc,
        (__attribute__((address_space(3))) unsigned int*)ldst,
        16, 0, 0);
}

// row-major qk frag load: elems 8g+i at col base (valid < 20), row stride NQK
__device__ __forceinline__ short8 load_qk_frag(const ushort* rowptr, int colbase, int g, bool rowvalid) {
    U32S8 v;
    v.s8 = (short8){0,0,0,0,0,0,0,0};
    if (rowvalid && g < 3) {
        const ushort* src = rowptr + colbase;
        if (g < 2) {
            v.h[0] = *(const short4v*)src;
            v.h[1] = *(const short4v*)(src + 4);
        } else {
            v.h[0] = *(const short4v*)src;
        }
    }
    return v.s8;
}

// ---------- prep: emb fp32 [V][300] -> bf16 [V][320] zero-padded ----------
__global__ void prep_emb(const float* __restrict__ emb, ushort* __restrict__ dst) {
    size_t gid = (size_t)blockIdx.x * 256 + threadIdx.x;
    size_t total8 = (size_t)VOCAB * (KP / 8);
    if (gid >= total8) return;
    size_t e0 = gid * 8;
    int row = (int)(e0 / KP);
    int c   = (int)(e0 - (size_t)row * KP);
    unsigned w[4] = {0, 0, 0, 0};
    if (c + 8 <= 300) {
        const float4* s = (const float4*)(emb + (size_t)row * 300 + c);
        float4 v0 = s[0], v1 = s[1];
        w[0] = pack2bf(v0.x, v0.y); w[1] = pack2bf(v0.z, v0.w);
        w[2] = pack2bf(v1.x, v1.y); w[3] = pack2bf(v1.z, v1.w);
    } else if (c < 300) {
        const float* s = emb + (size_t)row * 300;
        ushort tmp[8];
        #pragma unroll
        for (int i = 0; i < 8; ++i) tmp[i] = (c + i < 300) ? f2bf(s[c + i]) : (ushort)0;
        w[0] = tmp[0] | ((unsigned)tmp[1] << 16);
        w[1] = tmp[2] | ((unsigned)tmp[3] << 16);
        w[2] = tmp[4] | ((unsigned)tmp[5] << 16);
        w[3] = tmp[6] | ((unsigned)tmp[7] << 16);
    }
    *(unsigned*)(dst + e0)     = w[0];
    *(unsigned*)(dst + e0 + 2) = w[1];
    *(unsigned*)(dst + e0 + 4) = w[2];
    *(unsigned*)(dst + e0 + 6) = w[3];
}

// ---------- weight prep: W[k][n] fp32 -> WT[p][n][k] bf16, zero-padded ----------
__global__ void prep_qkv(const float* __restrict__ Wq, const float* __restrict__ Wk,
                         const float* __restrict__ Wv, ushort* __restrict__ dst, int P) {
    size_t i = (size_t)blockIdx.x * 256 + threadIdx.x;
    size_t total = (size_t)P * NQKV * KP;
    if (i >= total) return;
    int k = (int)(i % KP);
    int n = (int)((i / KP) % NQKV);
    int p = (int)(i / ((size_t)KP * NQKV));
    float v = 0.f;
    if (k < 300 && n < 900) {
        const float* W = (n < 300) ? Wq : (n < 600 ? Wk : Wv);
        int nn = n % 300;
        v = W[((size_t)p * 300 + k) * 300 + nn];
    }
    dst[i] = f2bf(v);
}

__global__ void prep_wp(const float* __restrict__ Wp, ushort* __restrict__ dst, int P) {
    size_t i = (size_t)blockIdx.x * 256 + threadIdx.x;
    size_t total = (size_t)P * NWP * KP;
    if (i >= total) return;
    int k = (int)(i % KP);
    int a = (int)((i / KP) % NWP);
    int p = (int)(i / ((size_t)KP * NWP));
    float v = 0.f;
    if (k < 300 && a < 200) v = Wp[((size_t)p * 300 + k) * 200 + a];
    dst[i] = f2bf(v);
}

// ---------- K2: 128x128 QKV GEMM, global_load_lds staging, row-major qk epilogue ----------
template<int LQ, bool GATHER>
__global__ __launch_bounds__(256, 4)
void qkv_gemm(const ushort* __restrict__ src_bf,
              const int* __restrict__ tokens,
              const ushort* __restrict__ wt,      // [P_all][NQKV][KP]
              ushort* __restrict__ qk, ushort* __restrict__ vt,
              int p0, int P_all, int NPMT)
{
    constexpr int MT = (LQ == 30) ? 30 : 50;    // 128-row mtiles per p
    constexpr int VS = (LQ == 30) ? 32 : 64;    // V^T m-stride
    constexpr int TS = 136;                     // transpose-tile row stride

    __shared__ __align__(16) char SM[34816];    // A0|A1|B0|B1 (32KB); T (34.8KB) overlays
    __shared__ int TOK[128];

    const int group = blockIdx.x >> 6;
    const int w64   = blockIdx.x & 63;
    const int mt_g  = group * 8 + (w64 & 7);
    const int ntile = w64 >> 3;
    if (mt_g >= NPMT) return;
    const int mtile = mt_g % MT;
    const int p_l   = mt_g / MT;
    const int p_g   = p0 + p_l;
    const int t     = threadIdx.x;
    const int wave  = t >> 6, lane = t & 63;
    const int r = lane & 15, g = lane >> 4;
    const int qm = wave >> 1, qn = wave & 1;

    if (GATHER && t < 128) {
        int row = mtile * 128 + t;
        int b = row / LQ, l = row - b * LQ;
        TOK[t] = tokens[((size_t)b * P_all + p_g) * LQ + l];
    }
    __syncthreads();

    const int kcs   = (lane & 3) ^ ((lane >> 2) & 3);   // swizzled source chunk
    const int rowA0 = wave * 16 + (lane >> 2);
    const int rowA1 = 64 + rowA0;
    const ushort* wtp = wt + (size_t)p_g * NQKV * KP;

    const ushort *pA0, *pA1;
    if (GATHER) {
        pA0 = src_bf + (size_t)TOK[rowA0] * KP + kcs * 8;
        pA1 = src_bf + (size_t)TOK[rowA1] * KP + kcs * 8;
    } else {
        pA0 = src_bf + (size_t)(mtile * 128 + rowA0) * KP + kcs * 8;
        pA1 = src_bf + (size_t)(mtile * 128 + rowA1) * KP + kcs * 8;
    }
    const ushort* pB0 = wtp + (size_t)(ntile * 128 + rowA0) * KP + kcs * 8;
    const ushort* pB1 = wtp + (size_t)(ntile * 128 + rowA1) * KP + kcs * 8;

    auto stage = [&](int ks, int bufb) {
        int ko = ks * 32;
        char* base = SM + bufb * 8192;
        gl_lds16(pA0 + ko, (ushort*)(base + wave * 1024));
        gl_lds16(pA1 + ko, (ushort*)(base + 4096 + wave * 1024));
        char* baseB = SM + 16384 + bufb * 8192;
        gl_lds16(pB0 + ko, (ushort*)(baseB + wave * 1024));
        gl_lds16(pB1 + ko, (ushort*)(baseB + 4096 + wave * 1024));
    };

    f32x4 acc[4][4];
    #pragma unroll
    for (int i = 0; i < 4; ++i)
        #pragma unroll
        for (int j = 0; j < 4; ++j)
            acc[i][j] = (f32x4){0.f, 0.f, 0.f, 0.f};

    stage(0, 0);
    __syncthreads();
    int buf = 0;
    const int kx = g ^ (r & 3);
    for (int ks = 0; ks < 10; ++ks) {
        if (ks < 9) stage(ks + 1, buf ^ 1);
        const ushort* Ab = (const ushort*)(SM + buf * 8192);
        const ushort* Bb = (const ushort*)(SM + 16384 + buf * 8192);
        short8 af[4], bfr[4];
        #pragma unroll
        for (int fi = 0; fi < 4; ++fi)
            af[fi] = *(const short8*)&Ab[(qm * 64 + fi * 16 + r) * 32 + kx * 8];
        #pragma unroll
        for (int fj = 0; fj < 4; ++fj)
            bfr[fj] = *(const short8*)&Bb[(qn * 64 + fj * 16 + r) * 32 + kx * 8];
        #pragma unroll
        for (int fi = 0; fi < 4; ++fi)
            #pragma unroll
            for (int fj = 0; fj < 4; ++fj)
                acc[fi][fj] = __builtin_amdgcn_mfma_f32_16x16x32_bf16(af[fi], bfr[fj], acc[fi][fj], 0, 0, 0);
        __syncthreads();
        buf ^= 1;
    }

    // ---- epilogue: acc -> LDS tile T[128][TS], then coalesced global writes ----
    ushort* T = (ushort*)SM;
    #pragma unroll
    for (int fi = 0; fi < 4; ++fi) {
        #pragma unroll
        for (int fj = 0; fj < 4; ++fj) {
            int col  = qn * 64 + fj * 16 + r;
            int rowb = qm * 64 + fi * 16 + 4 * g;
            #pragma unroll
            for (int j = 0; j < 4; ++j)
                T[(rowb + j) * TS + col] = f2bf(acc[fi][fj][j]);
        }
    }
    __syncthreads();

    const int R0 = mtile * 128;
    const int N0 = ntile * 128;
    ushort* qkp = qk + (size_t)p_l * (128 * MT) * NQK;
    ushort* vtp = vt + (size_t)p_l * BATCH * 15 * 20 * VS;

    // qk region: cols [N0, min(600, N0+128)) -> 16B stores, 128B-aligned rows
    {
        int nqk = 600 - N0;
        if (nqk > 128) nqk = 128;
        if (nqk > 0) {
            int nch = nqk >> 3;
            for (int t2 = t; t2 < 128 * nch; t2 += 256) {
                int row = t2 / nch, cc = t2 - row * nch;
                short8 v = *(const short8*)&T[row * TS + cc * 8];
                *(short8*)&qkp[(size_t)(R0 + row) * NQK + N0 + cc * 8] = v;
            }
        }
    }
    // vt region: cols [max(600,N0), min(900,N0+128)) -> [b][h][jj][VS] l-runs
    {
        int c0 = 600 - N0; if (c0 < 0) c0 = 0;
        int c1 = 900 - N0; if (c1 > 128) c1 = 128;
        if (c1 > c0) {
            int nvt = c1 - c0;
            int b0 = R0 / LQ, b1 = (R0 + 127) / LQ;
            int nb = b1 - b0 + 1;
            for (int t2 = t; t2 < nvt * nb; t2 += 256) {
                int ci = t2 % nvt, bi = t2 / nvt;
                int c = c0 + ci;
                int vj = N0 + c - 600;
                int h = vj / 20, jj = vj - h * 20;
                int b = b0 + bi;
                int gr0 = b * LQ;      if (gr0 < R0) gr0 = R0;
                int gr1 = b * LQ + LQ; if (gr1 > R0 + 128) gr1 = R0 + 128;
                if (gr1 <= gr0) continue;
                int l0 = gr0 - b * LQ, l1 = gr1 - b * LQ;
                ushort* dst = vtp + (((size_t)b * 15 + h) * 20 + jj) * VS;
                int l = l0;
                while (l < l1) {
                    if ((l & 7) == 0 && l + 8 <= l1) {
                        U32S8 v;
                        #pragma unroll
                        for (int i = 0; i < 8; ++i)
                            v.e[i] = T[(b * LQ + l + i - R0) * TS + c];
                        *(short8*)&dst[l] = v.s8;
                        l += 8;
                    } else if ((l & 1) == 0 && l + 2 <= l1) {
                        unsigned v = (unsigned)T[(b * LQ + l - R0) * TS + c] |
                                     ((unsigned)T[(b * LQ + l + 1 - R0) * TS + c] << 16);
                        *(unsigned*)&dst[l] = v;
                        l += 2;
                    } else {
                        dst[l] = T[(b * LQ + l - R0) * TS + c];
                        l += 1;
                    }
                }
            }
        }
    }
}

// ---------- K3: fused attention + pooling per instance (L=30), pipelined head loop ----------
template<bool BF16OUT>
__global__ __launch_bounds__(256, 4)
void attn_pool30(const ushort* __restrict__ qk,    // [P_chunk][3840][640]
                 const ushort* __restrict__ vt,    // [P_chunk][B][15][640]
                 const ushort* __restrict__ wt_wp, // [P_all][208][320]
                 const float* __restrict__ bp, const float* __restrict__ qv,
                 float* __restrict__ outf, ushort* __restrict__ outbf,
                 int p0, int P_all)
{
    constexpr int CS = 328;
    __shared__ ushort C[32 * CS];      // 20,992 B
    __shared__ float  SL[32];
    __shared__ float  AW[32];

    const int tid  = threadIdx.x;
    const int wave = tid >> 6;
    const int lane = tid & 63;
    const int r = lane & 15, g = lane >> 4;
    const int p_l = blockIdx.x / BATCH;
    const int b   = blockIdx.x % BATCH;
    const int p_g = p0 + p_l;

    const ushort* qb  = qk + ((size_t)p_l * BATCH + b) * 30 * NQK;
    const ushort* vb  = vt + ((size_t)p_l * BATCH + b) * 15 * 640;
    const ushort* wpp = wt_wp + (size_t)p_g * NWP * KP;
    const short8 z8 = (short8){0,0,0,0,0,0,0,0};

    // round-0 fragment loads issued BEFORE LDS zeroing (latency hides under it)
    short8 q0 = load_qk_frag(qb + (size_t)(r) * NQK,      wave * 20 + 8 * g, g, r < 30);
    short8 q1 = load_qk_frag(qb + (size_t)(16 + r) * NQK, wave * 20 + 8 * g, g, 16 + r < 30);
    short8 k0 = load_qk_frag(qb + (size_t)(r) * NQK,      300 + wave * 20 + 8 * g, g, r < 30);
    short8 k1 = load_qk_frag(qb + (size_t)(16 + r) * NQK, 300 + wave * 20 + 8 * g, g, 16 + r < 30);
    short8 vf0 = *(const short8*)&vb[wave * 640 + r * 32 + 8 * g];
    short8 vf1 = (16 + r < 20) ? *(const short8*)&vb[wave * 640 + (16 + r) * 32 + 8 * g] : z8;

    for (int i = tid; i < 32 * CS / 8; i += 256) {
        *(short8*)&C[i * 8] = z8;
    }
    if (tid < 32) SL[tid] = 0.f;
    __syncthreads();

    #pragma unroll
    for (int hp = 0; hp < 4; ++hp) {
        const int head = wave + 4 * hp;
        const int nh   = head + 4;
        // issue next round's loads before this round's compute
        short8 nq0 = z8, nq1 = z8, nk0 = z8, nk1 = z8, nvf0 = z8, nvf1 = z8;
        if (hp < 3 && nh < 15) {
            nq0 = load_qk_frag(qb + (size_t)(r) * NQK,      nh * 20 + 8 * g, g, r < 30);
            nq1 = load_qk_frag(qb + (size_t)(16 + r) * NQK, nh * 20 + 8 * g, g, 16 + r < 30);
            nk0 = load_qk_frag(qb + (size_t)(r) * NQK,      300 + nh * 20 + 8 * g, g, r < 30);
            nk1 = load_qk_frag(qb + (size_t)(16 + r) * NQK, 300 + nh * 20 + 8 * g, g, 16 + r < 30);
            nvf0 = *(const short8*)&vb[nh * 640 + r * 32 + 8 * g];
            nvf1 = (16 + r < 20) ? *(const short8*)&vb[nh * 640 + (16 + r) * 32 + 8 * g] : z8;
        }

        if (head < 15) {
            f32x4 s0m0 = {0,0,0,0}, s0m1 = {0,0,0,0}, s1m0 = {0,0,0,0}, s1m1 = {0,0,0,0};
            s0m0 = __builtin_amdgcn_mfma_f32_16x16x32_bf16(k0, q0, s0m0, 0, 0, 0);
            s0m1 = __builtin_amdgcn_mfma_f32_16x16x32_bf16(k1, q0, s0m1, 0, 0, 0);
            s1m0 = __builtin_amdgcn_mfma_f32_16x16x32_bf16(k0, q1, s1m0, 0, 0, 0);
            s1m1 = __builtin_amdgcn_mfma_f32_16x16x32_bf16(k1, q1, s1m1, 0, 0, 0);

            float mx0 = -1e30f, mx1 = -1e30f;
            #pragma unroll
            for (int j = 0; j < 4; ++j) {
                s0m0[j] *= SCALE; s1m0[j] *= SCALE;
                float v01 = (16 + 4 * g + j < 30) ? s0m1[j] * SCALE : -1e30f;
                float v11 = (16 + 4 * g + j < 30) ? s1m1[j] * SCALE : -1e30f;
                s0m1[j] = v01; s1m1[j] = v11;
                mx0 = fmaxf(mx0, fmaxf(s0m0[j], v01));
                mx1 = fmaxf(mx1, fmaxf(s1m0[j], v11));
            }
            mx0 = fmaxf(mx0, __shfl_xor(mx0, 16, 64));
            mx0 = fmaxf(mx0, __shfl_xor(mx0, 32, 64));
            mx1 = fmaxf(mx1, __shfl_xor(mx1, 16, 64));
            mx1 = fmaxf(mx1, __shfl_xor(mx1, 32, 64));
            float sm0 = 0.f, sm1 = 0.f;
            #pragma unroll
            for (int j = 0; j < 4; ++j) {
                s0m0[j] = __expf(s0m0[j] - mx0); s0m1[j] = __expf(s0m1[j] - mx0);
                s1m0[j] = __expf(s1m0[j] - mx1); s1m1[j] = __expf(s1m1[j] - mx1);
                sm0 += s0m0[j] + s0m1[j];
                sm1 += s1m0[j] + s1m1[j];
            }
            sm0 += __shfl_xor(sm0, 16, 64); sm0 += __shfl_xor(sm0, 32, 64);
            sm1 += __shfl_xor(sm1, 16, 64); sm1 += __shfl_xor(sm1, 32, 64);
            float inv0 = 1.0f / sm0, inv1 = 1.0f / sm1;

            unsigned pk000 = pack2bf(s0m0[0] * inv0, s0m0[1] * inv0);
            unsigned pk001 = pack2bf(s0m0[2] * inv0, s0m0[3] * inv0);
            unsigned pk010 = pack2bf(s0m1[0] * inv0, s0m1[1] * inv0);
            unsigned pk011 = pack2bf(s0m1[2] * inv0, s0m1[3] * inv0);
            unsigned pk100 = pack2bf(s1m0[0] * inv1, s1m0[1] * inv1);
            unsigned pk101 = pack2bf(s1m0[2] * inv1, s1m0[3] * inv1);
            unsigned pk110 = pack2bf(s1m1[0] * inv1, s1m1[1] * inv1);
            unsigned pk111 = pack2bf(s1m1[2] * inv1, s1m1[3] * inv1);

            const int sA = r + 16 * (2 * (g & 1));
            const int sB = sA + 16;
            const bool hi = (g >> 1) != 0;
            #pragma unroll
            for (int lt = 0; lt < 2; ++lt) {
                unsigned q00 = lt ? pk100 : pk000, q01 = lt ? pk101 : pk001;
                unsigned q10 = lt ? pk110 : pk010, q11 = lt ? pk111 : pk011;
                unsigned a0 = __shfl((int)q00, sA, 64), a1 = __shfl((int)q01, sA, 64);
                unsigned a2 = __shfl((int)q10, sA, 64), a3 = __shfl((int)q11, sA, 64);
                unsigned b0 = __shfl((int)q00, sB, 64), b1 = __shfl((int)q01, sB, 64);
                unsigned b2 = __shfl((int)q10, sB, 64), b3 = __shfl((int)q11, sB, 64);
                U32S8 pf;
                pf.u[0] = hi ? a2 : a0;
                pf.u[1] = hi ? a3 : a1;
                pf.u[2] = hi ? b2 : b0;
                pf.u[3] = hi ? b3 : b1;
                int lrow = lt * 16 + r;
                #pragma unroll
                for (int nt = 0; nt < 2; ++nt) {
                    short8 vf = nt ? vf1 : vf0;
                    f32x4 c = {0.f, 0.f, 0.f, 0.f};
                    c = __builtin_amdgcn_mfma_f32_16x16x32_bf16(vf, pf.s8, c, 0, 0, 0);
                    if (lrow < 30) {
                        #pragma unroll
                        for (int j = 0; j < 4; ++j) {
                            int vj = nt * 16 + 4 * g + j;
                            if (vj < 20)
                                C[lrow * CS + head * 20 + vj] = f2bf(c[j]);
                        }
                    }
                }
            }
        }
        // rotate pipeline registers (fully unrolled -> static)
        q0 = nq0; q1 = nq1; k0 = nk0; k1 = nk1; vf0 = nvf0; vf1 = nvf1;
    }
    __syncthreads();

    for (int nt = wave; nt < 13; nt += 4) {
        int col = nt * 16 + r;
        const ushort* wrow = wpp + (size_t)col * KP + 8 * g;
        short8 breg[10];
        #pragma unroll
        for (int ks = 0; ks < 10; ++ks) breg[ks] = *(const short8*)(wrow + 32 * ks);
        float bpv = (col < 200) ? bp[p_g * 200 + col] : 0.f;
        float qvv = (col < 200) ? qv[p_g * 200 + col] : 0.f;

        f32x4 acc0 = {0.f, 0.f, 0.f, 0.f}, acc1 = {0.f, 0.f, 0.f, 0.f};
        #pragma unroll
        for (int ks = 0; ks < 10; ++ks) {
            short8 a0 = *(const short8*)&C[(r) * CS + ks * 32 + 8 * g];
            short8 a1 = *(const short8*)&C[(16 + r) * CS + ks * 32 + 8 * g];
            acc0 = __builtin_amdgcn_mfma_f32_16x16x32_bf16(a0, breg[ks], acc0, 0, 0, 0);
            acc1 = __builtin_amdgcn_mfma_f32_16x16x32_bf16(a1, breg[ks], acc1, 0, 0, 0);
        }
        #pragma unroll
        for (int j = 0; j < 4; ++j) {
            float s0 = tanhf(acc0[j] + bpv) * qvv;
            float s1 = tanhf(acc1[j] + bpv) * qvv;
            s0 += __shfl_xor(s0, 1, 64); s1 += __shfl_xor(s1, 1, 64);
            s0 += __shfl_xor(s0, 2, 64); s1 += __shfl_xor(s1, 2, 64);
            s0 += __shfl_xor(s0, 4, 64); s1 += __shfl_xor(s1, 4, 64);
            s0 += __shfl_xor(s0, 8, 64); s1 += __shfl_xor(s1, 8, 64);
            if (r == 0) {
                atomicAdd(&SL[4 * g + j], s0);
                atomicAdd(&SL[16 + 4 * g + j], s1);
            }
        }
    }
    __syncthreads();

    if (wave == 0) {
        float x = (lane < 30) ? SL[lane] : -1e30f;
        float mx = x;
        #pragma unroll
        for (int off = 1; off < 64; off <<= 1) mx = fmaxf(mx, __shfl_xor(mx, off, 64));
        float e = (lane < 30) ? __expf(x - mx) : 0.f;
        float sm = e;
        #pragma unroll
        for (int off = 1; off < 64; off <<= 1) sm += __shfl_xor(sm, off, 64);
        if (lane < 32) AW[lane] = e / sm;
    }
    __syncthreads();

    for (int c = tid; c < 300; c += 256) {
        float o = 0.f;
        #pragma unroll
        for (int l = 0; l < 30; ++l)
            o = fmaf(AW[l], bf2f(C[l * CS + c]), o);
        if (BF16OUT) outbf[((size_t)b * P_all + p_g) * KP + c] = f2bf(o);
        else         outf[((size_t)b * P_all + p_g) * 300 + c] = o;
    }
}

// ---------- K3b: user attention (row-major qk) ----------
__global__ __launch_bounds__(512, 1)
void attn50(const ushort* __restrict__ qk,   // [6400][640]
            const ushort* __restrict__ vt,   // [128][15][20][64]
            ushort* __restrict__ ctx)        // [128][64][320]
{
    __shared__ ushort P_l[8][64 * 68];

    const int tid  = threadIdx.x;
    const int wave = tid >> 6;
    const int lane = tid & 63;
    const int r = lane & 15, g = lane >> 4;
    const int b = blockIdx.x;

    const ushort* qb = qk + (size_t)b * 50 * NQK;
    ushort* pw = &P_l[wave][0];

    for (int hh = wave; hh < 15; hh += 8) {
        short8 qf[4], kf[4];
        #pragma unroll
        for (int t4 = 0; t4 < 4; ++t4) {
            qf[t4] = load_qk_frag(qb + (size_t)(t4 * 16 + r) * NQK, hh * 20 + 8 * g, g, true);
            kf[t4] = load_qk_frag(qb + (size_t)(t4 * 16 + r) * NQK, 300 + hh * 20 + 8 * g, g, true);
        }
        short8 vf[2][2];
        #pragma unroll
        for (int nt = 0; nt < 2; ++nt) {
            int vj = nt * 16 + r;
            #pragma unroll
            for (int ks = 0; ks < 2; ++ks) {
                if (vj < 20)
                    vf[nt][ks] = *(const short8*)&vt[(((size_t)b * 15 + hh) * 20 + vj) * 64 + ks * 32 + 8 * g];
                else
                    vf[nt][ks] = (short8){0,0,0,0,0,0,0,0};
            }
        }

        f32x4 s[4][4];
        #pragma unroll
        for (int qt = 0; qt < 4; ++qt)
            #pragma unroll
            for (int kt = 0; kt < 4; ++kt) {
                f32x4 z = {0.f, 0.f, 0.f, 0.f};
                s[qt][kt] = __builtin_amdgcn_mfma_f32_16x16x32_bf16(kf[kt], qf[qt], z, 0, 0, 0);
            }

        float mx[4], sm[4];
        #pragma unroll
        for (int qt = 0; qt < 4; ++qt) {
            float m = -1e30f;
            #pragma unroll
            for (int kt = 0; kt < 4; ++kt)
                #pragma unroll
                for (int j = 0; j < 4; ++j) {
                    int col = kt * 16 + 4 * g + j;
                    float v = (col < 50) ? s[qt][kt][j] * SCALE : -1e30f;
                    s[qt][kt][j] = v;
                    m = fmaxf(m, v);
                }
            m = fmaxf(m, __shfl_xor(m, 16, 64));
            m = fmaxf(m, __shfl_xor(m, 32, 64));
            mx[qt] = m;
            float sum = 0.f;
            #pragma unroll
            for (int kt = 0; kt < 4; ++kt)
                #pragma unroll
                for (int j = 0; j < 4; ++j) {
                    float e = __expf(s[qt][kt][j] - m);
                    s[qt][kt][j] = e;
                    sum += e;
                }
            sum += __shfl_xor(sum, 16, 64);
            sum += __shfl_xor(sum, 32, 64);
            sm[qt] = 1.0f / sum;
        }

        #pragma unroll
        for (int qt = 0; qt < 4; ++qt) {
            float inv = sm[qt];
            #pragma unroll
            for (int kt = 0; kt < 4; ++kt) {
                unsigned w0 = pack2bf(s[qt][kt][0] * inv, s[qt][kt][1] * inv);
                unsigned w1 = pack2bf(s[qt][kt][2] * inv, s[qt][kt][3] * inv);
                ushort* dst = pw + (qt * 16 + r) * 68 + kt * 16 + 4 * g;
                *(unsigned*)dst = w0;
                *(unsigned*)(dst + 2) = w1;
            }
        }
        asm volatile("s_waitcnt lgkmcnt(0)");
        __builtin_amdgcn_sched_barrier(0);

        #pragma unroll
        for (int lt = 0; lt < 4; ++lt) {
            short8 pf0 = *(const short8*)(pw + (lt * 16 + r) * 68 + 8 * g);
            short8 pf1 = *(const short8*)(pw + (lt * 16 + r) * 68 + 32 + 8 * g);
            int l = lt * 16 + r;
            #pragma unroll
            for (int nt = 0; nt < 2; ++nt) {
                f32x4 c = {0.f, 0.f, 0.f, 0.f};
                c = __builtin_amdgcn_mfma_f32_16x16x32_bf16(vf[nt][0], pf0, c, 0, 0, 0);
                c = __builtin_amdgcn_mfma_f32_16x16x32_bf16(vf[nt][1], pf1, c, 0, 0, 0);
                int vjb = nt * 16 + 4 * g;
                if (l < 50 && vjb < 17) {
                    unsigned w0 = pack2bf(c[0], c[1]);
                    unsigned w1 = pack2bf(c[2], c[3]);
                    ushort* d = ctx + ((size_t)b * 64 + l) * CTS + hh * 20 + vjb;
                    *(unsigned*)d = w0;
                    *(unsigned*)(d + 2) = w1;
                }
            }
        }
    }
}

// ---------- K4b: user pooling ----------
__global__ __launch_bounds__(256, 2)
void pool50(const ushort* __restrict__ ctx,   // [128][64][320]
            const ushort* __restrict__ wt_wp, // [208][320]
            const float* __restrict__ bp, const float* __restrict__ qv,
            float* __restrict__ user_rep)     // [128][300]
{
    __shared__ ushort Bt[2][208 * 40];
    __shared__ float  logit[128];
    __shared__ float  aw[128];

    const int tid  = threadIdx.x;
    const int wave = tid >> 6;
    const int lane = tid & 63;
    const int r = lane & 15, g = lane >> 4;

    const ushort* cbase = ctx + (size_t)blockIdx.x * 2 * 64 * CTS;

    auto stageB = [&](int ks, int buf) {
        for (int i = tid; i < 832; i += 256) {
            int n = i >> 2, kk = (i & 3) * 8;
            *(short8*)&Bt[buf][n * 40 + kk] = *(const short8*)&wt_wp[(size_t)n * KP + ks * 32 + kk];
        }
    };

    float bpr[13], qvr[13];
    #pragma unroll
    for (int nf = 0; nf < 13; ++nf) {
        int col = nf * 16 + r;
        bpr[nf] = (col < 200) ? bp[col] : 0.f;
        qvr[nf] = (col < 200) ? qv[col] : 0.f;
    }

    f32x4 acc[2][13];
    #pragma unroll
    for (int mf = 0; mf < 2; ++mf)
        #pragma unroll
        for (int nf = 0; nf < 13; ++nf)
            acc[mf][nf] = (f32x4){0.f, 0.f, 0.f, 0.f};

    stageB(0, 0);
    __syncthreads();
    int buf = 0;
    for (int ks = 0; ks < 10; ++ks) {
        if (ks < 9) stageB(ks + 1, buf ^ 1);
        short8 af[2];
        #pragma unroll
        for (int mf = 0; mf < 2; ++mf)
            af[mf] = *(const short8*)&cbase[(size_t)(wave * 32 + mf * 16 + r) * CTS + ks * 32 + 8 * g];
        #pragma unroll
        for (int mf = 0; mf < 2; ++mf)
            #pragma unroll
            for (int nf = 0; nf < 13; ++nf) {
                short8 bf = *(const short8*)&Bt[buf][(nf * 16 + r) * 40 + 8 * g];
                acc[mf][nf] = __builtin_amdgcn_mfma_f32_16x16x32_bf16(af[mf], bf, acc[mf][nf], 0, 0, 0);
            }
        __syncthreads();
        buf ^= 1;
    }

    #pragma unroll
    for (int mf = 0; mf < 2; ++mf) {
        #pragma unroll
        for (int j = 0; j < 4; ++j) {
            float s = 0.f;
            #pragma unroll
            for (int nf = 0; nf < 13; ++nf)
                s += tanhf(acc[mf][nf][j] + bpr[nf]) * qvr[nf];
            s += __shfl_xor(s, 1, 64);
            s += __shfl_xor(s, 2, 64);
            s += __shfl_xor(s, 4, 64);
            s += __shfl_xor(s, 8, 64);
            if (r == 0) logit[wave * 32 + mf * 16 + 4 * g + j] = s;
        }
    }
    __syncthreads();

    if (wave < 2) {
        float x = (lane < 50) ? logit[wave * 64 + lane] : -1e30f;
        float mx = x;
        #pragma unroll
        for (int off = 1; off < 64; off <<= 1) mx = fmaxf(mx, __shfl_xor(mx, off, 64));
        float e = (lane < 50) ? __expf(x - mx) : 0.f;
        float sm = e;
        #pragma unroll
        for (int off = 1; off < 64; off <<= 1) sm += __shfl_xor(sm, off, 64);
        aw[wave * 64 + lane] = e / sm;
    }
    __syncthreads();

    for (int idx = tid; idx < 2 * 300; idx += 256) {
        int inst = idx / 300, c = idx - inst * 300;
        const ushort* crow = cbase + (size_t)inst * 64 * CTS + c;
        float o = 0.f;
        #pragma unroll
        for (int l = 0; l < 50; ++l)
            o = fmaf(aw[inst * 64 + l], bf2f(crow[(size_t)l * CTS]), o);
        int b = blockIdx.x * 2 + inst;
        user_rep[(size_t)b * 300 + c] = o;
    }
}

// ---------- final scoring ----------
__global__ __launch_bounds__(320)
void score_kernel(const float* __restrict__ user_rep, const float* __restrict__ cand_enc,
                  float* __restrict__ out)
{
    __shared__ float sc[NCAND];
    int b = blockIdx.x;
    int w = threadIdx.x >> 6;
    int lane = threadIdx.x & 63;
    float partial = 0.f;
    for (int d = lane; d < 300; d += 64)
        partial = fmaf(user_rep[b * 300 + d], cand_enc[((size_t)b * NCAND + w) * 300 + d], partial);
    for (int off = 32; off > 0; off >>= 1)
        partial += __shfl_down(partial, off, 64);
    if (lane == 0) sc[w] = partial;
    __syncthreads();
    if (threadIdx.x == 0) {
        float mx = -1e30f;
        for (int c = 0; c < NCAND; ++c) mx = fmaxf(mx, sc[c]);
        float s = 0.f; float e[NCAND];
        for (int c = 0; c < NCAND; ++c) { e[c] = __expf(sc[c] - mx); s += e[c]; }
        float inv = 1.0f / s;
        for (int c = 0; c < NCAND; ++c) out[b * NCAND + c] = e[c] * inv;
    }
}

extern "C" void kernel_launch(void* const* d_in, const int* in_sizes, int n_in,
                              void* d_out, int out_size, void* d_ws, size_t ws_size,
                              hipStream_t stream) {
    const int*   news_input = (const int*)d_in[0];
    const int*   candidates = (const int*)d_in[1];
    const float* emb        = (const float*)d_in[2];
    const float* his_Wq  = (const float*)d_in[3];
    const float* his_Wk  = (const float*)d_in[4];
    const float* his_Wv  = (const float*)d_in[5];
    const float* his_Wp  = (const float*)d_in[6];
    const float* his_bp  = (const float*)d_in[7];
    const float* his_qv  = (const float*)d_in[8];
    const float* cand_Wq = (const float*)d_in[9];
    const float* cand_Wk = (const float*)d_in[10];
    const float* cand_Wv = (const float*)d_in[11];
    const float* cand_Wp = (const float*)d_in[12];
    const float* cand_bp = (const float*)d_in[13];
    const float* cand_qv = (const float*)d_in[14];
    const float* usr_Wq  = (const float*)d_in[15];
    const float* usr_Wk  = (const float*)d_in[16];
    const float* usr_Wv  = (const float*)d_in[17];
    const float* usr_Wp  = (const float*)d_in[18];
    const float* usr_bp  = (const float*)d_in[19];
    const float* usr_qv  = (const float*)d_in[20];
    float* out = (float*)d_out;

    char* ws = (char*)d_ws;
    ushort* emb_bf      = (ushort*)ws;            ws += (size_t)VOCAB * KP * 2;
    ushort* news_enc_bf = (ushort*)ws;            ws += (size_t)BATCH * NHIS * KP * 2;
    float* cand_enc = (float*)ws;                 ws += (size_t)BATCH * NCAND * 300 * 4;
    float* user_rep = (float*)ws;                 ws += (size_t)BATCH * 300 * 4;
    ushort* his_qkvT  = (ushort*)ws;              ws += (size_t)NHIS * NQKV * KP * 2;
    ushort* his_wpT   = (ushort*)ws;              ws += (size_t)NHIS * NWP  * KP * 2;
    ushort* cand_qkvT = (ushort*)ws;              ws += (size_t)NCAND * NQKV * KP * 2;
    ushort* cand_wpT  = (ushort*)ws;              ws += (size_t)NCAND * NWP  * KP * 2;
    ushort* usr_qkvT  = (ushort*)ws;              ws += (size_t)NQKV * KP * 2;
    ushort* usr_wpT   = (ushort*)ws;              ws += (size_t)NWP  * KP * 2;

    size_t used = (size_t)(ws - (char*)d_ws);
    size_t avail = (ws_size > used) ? (ws_size - used) : 0;
    size_t qk_pp  = (size_t)3840 * NQK * 2;
    size_t vt_pp  = (size_t)BATCH * 15 * 640 * 2;
    size_t per_p  = qk_pp + vt_pp;
    int CP = (int)(avail / per_p);
    if (CP > 50) CP = 50;
    if (CP < 3) CP = 3;   // user overlay (~16 MB) needs >= 3*per_p

    ushort* qk_ws  = (ushort*)ws;
    ushort* vt_ws  = qk_ws + (size_t)CP * 3840 * NQK;

    ushort* qk_u  = qk_ws;                                // [6400][640]
    ushort* vt_u  = qk_u + (size_t)6400 * NQK;            // [128][15][20][64]
    ushort* ctx_u = vt_u + (size_t)BATCH * 15 * 20 * 64;  // [128][64][320]

    auto blocks = [](size_t total) { return (int)((total + 255) / 256); };
    auto qkv_grid = [](int npmt) { return ((npmt + 7) / 8) * 64; };

    hipMemsetAsync(news_enc_bf, 0, (size_t)BATCH * NHIS * KP * 2, stream);
    prep_emb<<<blocks((size_t)VOCAB * (KP / 8)), 256, 0, stream>>>(emb, emb_bf);
    prep_qkv<<<blocks((size_t)NHIS  * NQKV * KP), 256, 0, stream>>>(his_Wq,  his_Wk,  his_Wv,  his_qkvT,  NHIS);
    prep_qkv<<<blocks((size_t)NCAND * NQKV * KP), 256, 0, stream>>>(cand_Wq, cand_Wk, cand_Wv, cand_qkvT, NCAND);
    prep_qkv<<<blocks((size_t)1     * NQKV * KP), 256, 0, stream>>>(usr_Wq,  usr_Wk,  usr_Wv,  usr_qkvT,  1);
    prep_wp <<<blocks((size_t)NHIS  * NWP  * KP), 256, 0, stream>>>(his_Wp,  his_wpT,  NHIS);
    prep_wp <<<blocks((size_t)NCAND * NWP  * KP), 256, 0, stream>>>(cand_Wp, cand_wpT, NCAND);
    prep_wp <<<blocks((size_t)1     * NWP  * KP), 256, 0, stream>>>(usr_Wp,  usr_wpT,  1);

    for (int p0 = 0; p0 < NHIS; p0 += CP) {
        int cp = (NHIS - p0 < CP) ? (NHIS - p0) : CP;
        int npmt = cp * 30;
        qkv_gemm<30, true><<<qkv_grid(npmt), 256, 0, stream>>>(emb_bf, news_input, his_qkvT,
                                                               qk_ws, vt_ws, p0, NHIS, npmt);
        attn_pool30<true><<<cp * BATCH, 256, 0, stream>>>(qk_ws, vt_ws, his_wpT, his_bp, his_qv,
                                                          nullptr, news_enc_bf, p0, NHIS);
    }
    {
        int npmt = NCAND * 30;
        qkv_gemm<30, true><<<qkv_grid(npmt), 256, 0, stream>>>(emb_bf, candidates, cand_qkvT,
                                                               qk_ws, vt_ws, 0, NCAND, npmt);
        attn_pool30<false><<<NCAND * BATCH, 256, 0, stream>>>(qk_ws, vt_ws, cand_wpT, cand_bp, cand_qv,
                                                              cand_enc, nullptr, 0, NCAND);
    }

    // user encoder
    hipMemsetAsync(vt_u, 0, (size_t)BATCH * 15 * 20 * 64 * 2, stream);
    qkv_gemm<50, false><<<qkv_grid(50), 256, 0, stream>>>(news_enc_bf, nullptr, usr_qkvT,
                                                          qk_u, vt_u, 0, 1, 50);
    attn50<<<BATCH, 512, 0, stream>>>(qk_u, vt_u, ctx_u);
    pool50<<<64, 256, 0, stream>>>(ctx_u, usr_wpT, usr_bp, usr_qv, user_rep);

    score_kernel<<<BATCH, 320, 0, stream>>>(user_rep, cand_enc, out);
}

// Round 21
// 797.474 us; speedup vs baseline: 1.0982x; 1.0982x over previous
//
#include <hip/hip_runtime.h>
#include <math.h>

typedef __attribute__((ext_vector_type(8))) short short8;
typedef __attribute__((ext_vector_type(4))) short short4v;
typedef __attribute__((ext_vector_type(4))) float f32x4;

union U32S8 { unsigned u[4]; short8 s8; ushort e[8]; short4v h[2]; };

#define BATCH 128
#define NHIS  50
#define NCAND 5
#define KP    320    // padded K stride (elems) for weights, emb_bf, news_enc_bf
#define NQKV  1024   // padded N for [Wq|Wk|Wv] weight buffer (8 exact 128-panels)
#define NWP   208    // padded N for Wp
#define NQK   640    // Q|K row width (1280B rows, 128B-aligned)
#define CTS   320    // user ctx row stride
#define VOCAB 60000
#define SCALE 0.22360679774997896f  // 1/sqrt(20)

__device__ __forceinline__ ushort f2bf(float f) {
    union { float f; unsigned u; } v; v.f = f;
    return (ushort)((v.u + 0x7fffu + ((v.u >> 16) & 1u)) >> 16);
}
__device__ __forceinline__ unsigned pack2bf(float lo, float hi) {
    return (unsigned)f2bf(lo) | ((unsigned)f2bf(hi) << 16);
}
__device__ __forceinline__ float bf2f(ushort u) {
    union { float f; unsigned u; } v; v.u = ((unsigned)u) << 16;
    return v.f;
}

// async global -> LDS, 16B per lane (dest = wave-uniform base + lane*16)
__device__ __forceinline__ void gl_lds16(const ushort* gsrc, ushort* ldst) {
    __builtin_amdgcn_global_load_lds(
        (const __attribute__((address_space(1))) unsigned int*)gsrc,
        (__attribute__((address_space(3))) unsigned int*)ldst,
        16, 0, 0);
}

// row-major qk frag load: elems 8g+i at col base (valid < 20), row stride NQK
__device__ __forceinline__ short8 load_qk_frag(const ushort* rowptr, int colbase, int g, bool rowvalid) {
    U32S8 v;
    v.s8 = (short8){0,0,0,0,0,0,0,0};
    if (rowvalid && g < 3) {
        const ushort* src = rowptr + colbase;
        if (g < 2) {
            v.h[0] = *(const short4v*)src;
            v.h[1] = *(const short4v*)(src + 4);
        } else {
            v.h[0] = *(const short4v*)src;
        }
    }
    return v.s8;
}

// ---------- prep: emb fp32 [V][300] -> bf16 [V][320] zero-padded ----------
__global__ void prep_emb(const float* __restrict__ emb, ushort* __restrict__ dst) {
    size_t gid = (size_t)blockIdx.x * 256 + threadIdx.x;
    size_t total8 = (size_t)VOCAB * (KP / 8);
    if (gid >= total8) return;
    size_t e0 = gid * 8;
    int row = (int)(e0 / KP);
    int c   = (int)(e0 - (size_t)row * KP);
    unsigned w[4] = {0, 0, 0, 0};
    if (c + 8 <= 300) {
        const float4* s = (const float4*)(emb + (size_t)row * 300 + c);
        float4 v0 = s[0], v1 = s[1];
        w[0] = pack2bf(v0.x, v0.y); w[1] = pack2bf(v0.z, v0.w);
        w[2] = pack2bf(v1.x, v1.y); w[3] = pack2bf(v1.z, v1.w);
    } else if (c < 300) {
        const float* s = emb + (size_t)row * 300;
        ushort tmp[8];
        #pragma unroll
        for (int i = 0; i < 8; ++i) tmp[i] = (c + i < 300) ? f2bf(s[c + i]) : (ushort)0;
        w[0] = tmp[0] | ((unsigned)tmp[1] << 16);
        w[1] = tmp[2] | ((unsigned)tmp[3] << 16);
        w[2] = tmp[4] | ((unsigned)tmp[5] << 16);
        w[3] = tmp[6] | ((unsigned)tmp[7] << 16);
    }
    *(unsigned*)(dst + e0)     = w[0];
    *(unsigned*)(dst + e0 + 2) = w[1];
    *(unsigned*)(dst + e0 + 4) = w[2];
    *(unsigned*)(dst + e0 + 6) = w[3];
}

// ---------- weight prep: W[k][n] fp32 -> WT[p][n][k] bf16, zero-padded ----------
__global__ void prep_qkv(const float* __restrict__ Wq, const float* __restrict__ Wk,
                         const float* __restrict__ Wv, ushort* __restrict__ dst, int P) {
    size_t i = (size_t)blockIdx.x * 256 + threadIdx.x;
    size_t total = (size_t)P * NQKV * KP;
    if (i >= total) return;
    int k = (int)(i % KP);
    int n = (int)((i / KP) % NQKV);
    int p = (int)(i / ((size_t)KP * NQKV));
    float v = 0.f;
    if (k < 300 && n < 900) {
        const float* W = (n < 300) ? Wq : (n < 600 ? Wk : Wv);
        int nn = n % 300;
        v = W[((size_t)p * 300 + k) * 300 + nn];
    }
    dst[i] = f2bf(v);
}

__global__ void prep_wp(const float* __restrict__ Wp, ushort* __restrict__ dst, int P) {
    size_t i = (size_t)blockIdx.x * 256 + threadIdx.x;
    size_t total = (size_t)P * NWP * KP;
    if (i >= total) return;
    int k = (int)(i % KP);
    int a = (int)((i / KP) % NWP);
    int p = (int)(i / ((size_t)KP * NWP));
    float v = 0.f;
    if (k < 300 && a < 200) v = Wp[((size_t)p * 300 + k) * 200 + a];
    dst[i] = f2bf(v);
}

// ---------- K2: 128x128 QKV GEMM, global_load_lds staging, row-major qk epilogue ----------
template<int LQ, bool GATHER>
__global__ __launch_bounds__(256, 4)
void qkv_gemm(const ushort* __restrict__ src_bf,
              const int* __restrict__ tokens,
              const ushort* __restrict__ wt,      // [P_all][NQKV][KP]
              ushort* __restrict__ qk, ushort* __restrict__ vt,
              int p0, int P_all, int NPMT)
{
    constexpr int MT = (LQ == 30) ? 30 : 50;    // 128-row mtiles per p
    constexpr int VS = (LQ == 30) ? 32 : 64;    // V^T m-stride
    constexpr int TS = 136;                     // transpose-tile row stride

    __shared__ __align__(16) char SM[34816];    // A0|A1|B0|B1 (32KB); T (34.8KB) overlays
    __shared__ int TOK[128];

    const int group = blockIdx.x >> 6;
    const int w64   = blockIdx.x & 63;
    const int mt_g  = group * 8 + (w64 & 7);
    const int ntile = w64 >> 3;
    if (mt_g >= NPMT) return;
    const int mtile = mt_g % MT;
    const int p_l   = mt_g / MT;
    const int p_g   = p0 + p_l;
    const int t     = threadIdx.x;
    const int wave  = t >> 6, lane = t & 63;
    const int r = lane & 15, g = lane >> 4;
    const int qm = wave >> 1, qn = wave & 1;

    if (GATHER && t < 128) {
        int row = mtile * 128 + t;
        int b = row / LQ, l = row - b * LQ;
        TOK[t] = tokens[((size_t)b * P_all + p_g) * LQ + l];
    }
    __syncthreads();

    const int kcs   = (lane & 3) ^ ((lane >> 2) & 3);   // swizzled source chunk
    const int rowA0 = wave * 16 + (lane >> 2);
    const int rowA1 = 64 + rowA0;
    const ushort* wtp = wt + (size_t)p_g * NQKV * KP;

    const ushort *pA0, *pA1;
    if (GATHER) {
        pA0 = src_bf + (size_t)TOK[rowA0] * KP + kcs * 8;
        pA1 = src_bf + (size_t)TOK[rowA1] * KP + kcs * 8;
    } else {
        pA0 = src_bf + (size_t)(mtile * 128 + rowA0) * KP + kcs * 8;
        pA1 = src_bf + (size_t)(mtile * 128 + rowA1) * KP + kcs * 8;
    }
    const ushort* pB0 = wtp + (size_t)(ntile * 128 + rowA0) * KP + kcs * 8;
    const ushort* pB1 = wtp + (size_t)(ntile * 128 + rowA1) * KP + kcs * 8;

    auto stage = [&](int ks, int bufb) {
        int ko = ks * 32;
        char* base = SM + bufb * 8192;
        gl_lds16(pA0 + ko, (ushort*)(base + wave * 1024));
        gl_lds16(pA1 + ko, (ushort*)(base + 4096 + wave * 1024));
        char* baseB = SM + 16384 + bufb * 8192;
        gl_lds16(pB0 + ko, (ushort*)(baseB + wave * 1024));
        gl_lds16(pB1 + ko, (ushort*)(baseB + 4096 + wave * 1024));
    };

    f32x4 acc[4][4];
    #pragma unroll
    for (int i = 0; i < 4; ++i)
        #pragma unroll
        for (int j = 0; j < 4; ++j)
            acc[i][j] = (f32x4){0.f, 0.f, 0.f, 0.f};

    stage(0, 0);
    __syncthreads();
    int buf = 0;
    const int kx = g ^ (r & 3);
    for (int ks = 0; ks < 10; ++ks) {
        if (ks < 9) stage(ks + 1, buf ^ 1);
        const ushort* Ab = (const ushort*)(SM + buf * 8192);
        const ushort* Bb = (const ushort*)(SM + 16384 + buf * 8192);
        short8 af[4], bfr[4];
        #pragma unroll
        for (int fi = 0; fi < 4; ++fi)
            af[fi] = *(const short8*)&Ab[(qm * 64 + fi * 16 + r) * 32 + kx * 8];
        #pragma unroll
        for (int fj = 0; fj < 4; ++fj)
            bfr[fj] = *(const short8*)&Bb[(qn * 64 + fj * 16 + r) * 32 + kx * 8];
        #pragma unroll
        for (int fi = 0; fi < 4; ++fi)
            #pragma unroll
            for (int fj = 0; fj < 4; ++fj)
                acc[fi][fj] = __builtin_amdgcn_mfma_f32_16x16x32_bf16(af[fi], bfr[fj], acc[fi][fj], 0, 0, 0);
        __syncthreads();
        buf ^= 1;
    }

    // ---- epilogue: acc -> LDS tile T[128][TS], then coalesced global writes ----
    ushort* T = (ushort*)SM;
    #pragma unroll
    for (int fi = 0; fi < 4; ++fi) {
        #pragma unroll
        for (int fj = 0; fj < 4; ++fj) {
            int col  = qn * 64 + fj * 16 + r;
            int rowb = qm * 64 + fi * 16 + 4 * g;
            #pragma unroll
            for (int j = 0; j < 4; ++j)
                T[(rowb + j) * TS + col] = f2bf(acc[fi][fj][j]);
        }
    }
    __syncthreads();

    const int R0 = mtile * 128;
    const int N0 = ntile * 128;
    ushort* qkp = qk + (size_t)p_l * (128 * MT) * NQK;
    ushort* vtp = vt + (size_t)p_l * BATCH * 15 * 20 * VS;

    // qk region: cols [N0, min(600, N0+128)) -> 16B stores, 128B-aligned rows
    {
        int nqk = 600 - N0;
        if (nqk > 128) nqk = 128;
        if (nqk > 0) {
            int nch = nqk >> 3;
            for (int t2 = t; t2 < 128 * nch; t2 += 256) {
                int row = t2 / nch, cc = t2 - row * nch;
                short8 v = *(const short8*)&T[row * TS + cc * 8];
                *(short8*)&qkp[(size_t)(R0 + row) * NQK + N0 + cc * 8] = v;
            }
        }
    }
    // vt region: cols [max(600,N0), min(900,N0+128)) -> [b][h][jj][VS] l-runs
    {
        int c0 = 600 - N0; if (c0 < 0) c0 = 0;
        int c1 = 900 - N0; if (c1 > 128) c1 = 128;
        if (c1 > c0) {
            int nvt = c1 - c0;
            int b0 = R0 / LQ, b1 = (R0 + 127) / LQ;
            int nb = b1 - b0 + 1;
            for (int t2 = t; t2 < nvt * nb; t2 += 256) {
                int ci = t2 % nvt, bi = t2 / nvt;
                int c = c0 + ci;
                int vj = N0 + c - 600;
                int h = vj / 20, jj = vj - h * 20;
                int b = b0 + bi;
                int gr0 = b * LQ;      if (gr0 < R0) gr0 = R0;
                int gr1 = b * LQ + LQ; if (gr1 > R0 + 128) gr1 = R0 + 128;
                if (gr1 <= gr0) continue;
                int l0 = gr0 - b * LQ, l1 = gr1 - b * LQ;
                ushort* dst = vtp + (((size_t)b * 15 + h) * 20 + jj) * VS;
                int l = l0;
                while (l < l1) {
                    if ((l & 7) == 0 && l + 8 <= l1) {
                        U32S8 v;
                        #pragma unroll
                        for (int i = 0; i < 8; ++i)
                            v.e[i] = T[(b * LQ + l + i - R0) * TS + c];
                        *(short8*)&dst[l] = v.s8;
                        l += 8;
                    } else if ((l & 1) == 0 && l + 2 <= l1) {
                        unsigned v = (unsigned)T[(b * LQ + l - R0) * TS + c] |
                                     ((unsigned)T[(b * LQ + l + 1 - R0) * TS + c] << 16);
                        *(unsigned*)&dst[l] = v;
                        l += 2;
                    } else {
                        dst[l] = T[(b * LQ + l - R0) * TS + c];
                        l += 1;
                    }
                }
            }
        }
    }
}

// ---------- K3: fused attention + pooling per instance (L=30), Wp prefetch ----------
template<bool BF16OUT>
__global__ __launch_bounds__(256, 4)
void attn_pool30(const ushort* __restrict__ qk,    // [P_chunk][3840][640]
                 const ushort* __restrict__ vt,    // [P_chunk][B][15][640]
                 const ushort* __restrict__ wt_wp, // [P_all][208][320]
                 const float* __restrict__ bp, const float* __restrict__ qv,
                 float* __restrict__ outf, ushort* __restrict__ outbf,
                 int p0, int P_all)
{
    constexpr int CS = 328;
    __shared__ ushort C[32 * CS];      // 20,992 B
    __shared__ float  SL[32];
    __shared__ float  AW[32];

    const int tid  = threadIdx.x;
    const int wave = tid >> 6;
    const int lane = tid & 63;
    const int r = lane & 15, g = lane >> 4;
    const int p_l = blockIdx.x / BATCH;
    const int b   = blockIdx.x % BATCH;
    const int p_g = p0 + p_l;

    const ushort* qb  = qk + ((size_t)p_l * BATCH + b) * 30 * NQK;
    const ushort* vb  = vt + ((size_t)p_l * BATCH + b) * 15 * 640;
    const ushort* wpp = wt_wp + (size_t)p_g * NWP * KP;

    // prefetch wave's first Wp n-tile (latency hides under attention)
    short8 breg0[10];
    {
        int col = wave * 16 + r;
        const ushort* wrow = wpp + (size_t)col * KP + 8 * g;
        #pragma unroll
        for (int ks = 0; ks < 10; ++ks) breg0[ks] = *(const short8*)(wrow + 32 * ks);
    }

    for (int i = tid; i < 32 * CS / 8; i += 256) {
        short8 z = (short8){0,0,0,0,0,0,0,0};
        *(short8*)&C[i * 8] = z;
    }
    if (tid < 32) SL[tid] = 0.f;
    __syncthreads();

    for (int hp = 0; hp < 4; ++hp) {
        int head = wave + 4 * hp;
        if (head < 15) {
            short8 q0 = load_qk_frag(qb + (size_t)(r) * NQK,      head * 20 + 8 * g, g, r < 30);
            short8 q1 = load_qk_frag(qb + (size_t)(16 + r) * NQK, head * 20 + 8 * g, g, 16 + r < 30);
            short8 k0 = load_qk_frag(qb + (size_t)(r) * NQK,      300 + head * 20 + 8 * g, g, r < 30);
            short8 k1 = load_qk_frag(qb + (size_t)(16 + r) * NQK, 300 + head * 20 + 8 * g, g, 16 + r < 30);
            short8 vf0 = *(const short8*)&vb[head * 640 + r * 32 + 8 * g];
            short8 vf1 = (16 + r < 20) ? *(const short8*)&vb[head * 640 + (16 + r) * 32 + 8 * g]
                                       : (short8){0,0,0,0,0,0,0,0};

            f32x4 s0m0 = {0,0,0,0}, s0m1 = {0,0,0,0}, s1m0 = {0,0,0,0}, s1m1 = {0,0,0,0};
            s0m0 = __builtin_amdgcn_mfma_f32_16x16x32_bf16(k0, q0, s0m0, 0, 0, 0);
            s0m1 = __builtin_amdgcn_mfma_f32_16x16x32_bf16(k1, q0, s0m1, 0, 0, 0);
            s1m0 = __builtin_amdgcn_mfma_f32_16x16x32_bf16(k0, q1, s1m0, 0, 0, 0);
            s1m1 = __builtin_amdgcn_mfma_f32_16x16x32_bf16(k1, q1, s1m1, 0, 0, 0);

            float mx0 = -1e30f, mx1 = -1e30f;
            #pragma unroll
            for (int j = 0; j < 4; ++j) {
                s0m0[j] *= SCALE; s1m0[j] *= SCALE;
                float v01 = (16 + 4 * g + j < 30) ? s0m1[j] * SCALE : -1e30f;
                float v11 = (16 + 4 * g + j < 30) ? s1m1[j] * SCALE : -1e30f;
                s0m1[j] = v01; s1m1[j] = v11;
                mx0 = fmaxf(mx0, fmaxf(s0m0[j], v01));
                mx1 = fmaxf(mx1, fmaxf(s1m0[j], v11));
            }
            mx0 = fmaxf(mx0, __shfl_xor(mx0, 16, 64));
            mx0 = fmaxf(mx0, __shfl_xor(mx0, 32, 64));
            mx1 = fmaxf(mx1, __shfl_xor(mx1, 16, 64));
            mx1 = fmaxf(mx1, __shfl_xor(mx1, 32, 64));
            float sm0 = 0.f, sm1 = 0.f;
            #pragma unroll
            for (int j = 0; j < 4; ++j) {
                s0m0[j] = __expf(s0m0[j] - mx0); s0m1[j] = __expf(s0m1[j] - mx0);
                s1m0[j] = __expf(s1m0[j] - mx1); s1m1[j] = __expf(s1m1[j] - mx1);
                sm0 += s0m0[j] + s0m1[j];
                sm1 += s1m0[j] + s1m1[j];
            }
            sm0 += __shfl_xor(sm0, 16, 64); sm0 += __shfl_xor(sm0, 32, 64);
            sm1 += __shfl_xor(sm1, 16, 64); sm1 += __shfl_xor(sm1, 32, 64);
            float inv0 = 1.0f / sm0, inv1 = 1.0f / sm1;

            unsigned pk000 = pack2bf(s0m0[0] * inv0, s0m0[1] * inv0);
            unsigned pk001 = pack2bf(s0m0[2] * inv0, s0m0[3] * inv0);
            unsigned pk010 = pack2bf(s0m1[0] * inv0, s0m1[1] * inv0);
            unsigned pk011 = pack2bf(s0m1[2] * inv0, s0m1[3] * inv0);
            unsigned pk100 = pack2bf(s1m0[0] * inv1, s1m0[1] * inv1);
            unsigned pk101 = pack2bf(s1m0[2] * inv1, s1m0[3] * inv1);
            unsigned pk110 = pack2bf(s1m1[0] * inv1, s1m1[1] * inv1);
            unsigned pk111 = pack2bf(s1m1[2] * inv1, s1m1[3] * inv1);

            const int sA = r + 16 * (2 * (g & 1));
            const int sB = sA + 16;
            const bool hi = (g >> 1) != 0;
            #pragma unroll
            for (int lt = 0; lt < 2; ++lt) {
                unsigned q00 = lt ? pk100 : pk000, q01 = lt ? pk101 : pk001;
                unsigned q10 = lt ? pk110 : pk010, q11 = lt ? pk111 : pk011;
                unsigned a0 = __shfl((int)q00, sA, 64), a1 = __shfl((int)q01, sA, 64);
                unsigned a2 = __shfl((int)q10, sA, 64), a3 = __shfl((int)q11, sA, 64);
                unsigned b0 = __shfl((int)q00, sB, 64), b1 = __shfl((int)q01, sB, 64);
                unsigned b2 = __shfl((int)q10, sB, 64), b3 = __shfl((int)q11, sB, 64);
                U32S8 pf;
                pf.u[0] = hi ? a2 : a0;
                pf.u[1] = hi ? a3 : a1;
                pf.u[2] = hi ? b2 : b0;
                pf.u[3] = hi ? b3 : b1;
                int lrow = lt * 16 + r;
                #pragma unroll
                for (int nt = 0; nt < 2; ++nt) {
                    short8 vf = nt ? vf1 : vf0;
                    f32x4 c = {0.f, 0.f, 0.f, 0.f};
                    c = __builtin_amdgcn_mfma_f32_16x16x32_bf16(vf, pf.s8, c, 0, 0, 0);
                    if (lrow < 30) {
                        #pragma unroll
                        for (int j = 0; j < 4; ++j) {
                            int vj = nt * 16 + 4 * g + j;
                            if (vj < 20)
                                C[lrow * CS + head * 20 + vj] = f2bf(c[j]);
                        }
                    }
                }
            }
        }
    }
    __syncthreads();

    for (int nt = wave; nt < 13; nt += 4) {
        int col = nt * 16 + r;
        short8 breg[10];
        if (nt == wave) {
            #pragma unroll
            for (int ks = 0; ks < 10; ++ks) breg[ks] = breg0[ks];
        } else {
            const ushort* wrow = wpp + (size_t)col * KP + 8 * g;
            #pragma unroll
            for (int ks = 0; ks < 10; ++ks) breg[ks] = *(const short8*)(wrow + 32 * ks);
        }
        float bpv = (col < 200) ? bp[p_g * 200 + col] : 0.f;
        float qvv = (col < 200) ? qv[p_g * 200 + col] : 0.f;

        f32x4 acc0 = {0.f, 0.f, 0.f, 0.f}, acc1 = {0.f, 0.f, 0.f, 0.f};
        #pragma unroll
        for (int ks = 0; ks < 10; ++ks) {
            short8 a0 = *(const short8*)&C[(r) * CS + ks * 32 + 8 * g];
            short8 a1 = *(const short8*)&C[(16 + r) * CS + ks * 32 + 8 * g];
            acc0 = __builtin_amdgcn_mfma_f32_16x16x32_bf16(a0, breg[ks], acc0, 0, 0, 0);
            acc1 = __builtin_amdgcn_mfma_f32_16x16x32_bf16(a1, breg[ks], acc1, 0, 0, 0);
        }
        #pragma unroll
        for (int j = 0; j < 4; ++j) {
            float s0 = tanhf(acc0[j] + bpv) * qvv;
            float s1 = tanhf(acc1[j] + bpv) * qvv;
            s0 += __shfl_xor(s0, 1, 64); s1 += __shfl_xor(s1, 1, 64);
            s0 += __shfl_xor(s0, 2, 64); s1 += __shfl_xor(s1, 2, 64);
            s0 += __shfl_xor(s0, 4, 64); s1 += __shfl_xor(s1, 4, 64);
            s0 += __shfl_xor(s0, 8, 64); s1 += __shfl_xor(s1, 8, 64);
            if (r == 0) {
                atomicAdd(&SL[4 * g + j], s0);
                atomicAdd(&SL[16 + 4 * g + j], s1);
            }
        }
    }
    __syncthreads();

    if (wave == 0) {
        float x = (lane < 30) ? SL[lane] : -1e30f;
        float mx = x;
        #pragma unroll
        for (int off = 1; off < 64; off <<= 1) mx = fmaxf(mx, __shfl_xor(mx, off, 64));
        float e = (lane < 30) ? __expf(x - mx) : 0.f;
        float sm = e;
        #pragma unroll
        for (int off = 1; off < 64; off <<= 1) sm += __shfl_xor(sm, off, 64);
        if (lane < 32) AW[lane] = e / sm;
    }
    __syncthreads();

    for (int c = tid; c < 300; c += 256) {
        float o = 0.f;
        #pragma unroll
        for (int l = 0; l < 30; ++l)
            o = fmaf(AW[l], bf2f(C[l * CS + c]), o);
        if (BF16OUT) outbf[((size_t)b * P_all + p_g) * KP + c] = f2bf(o);
        else         outf[((size_t)b * P_all + p_g) * 300 + c] = o;
    }
}

// ---------- K3b: user attention (row-major qk) ----------
__global__ __launch_bounds__(512, 1)
void attn50(const ushort* __restrict__ qk,   // [6400][640]
            const ushort* __restrict__ vt,   // [128][15][20][64]
            ushort* __restrict__ ctx)        // [128][64][320]
{
    __shared__ ushort P_l[8][64 * 68];

    const int tid  = threadIdx.x;
    const int wave = tid >> 6;
    const int lane = tid & 63;
    const int r = lane & 15, g = lane >> 4;
    const int b = blockIdx.x;

    const ushort* qb = qk + (size_t)b * 50 * NQK;
    ushort* pw = &P_l[wave][0];

    for (int hh = wave; hh < 15; hh += 8) {
        short8 qf[4], kf[4];
        #pragma unroll
        for (int t4 = 0; t4 < 4; ++t4) {
            qf[t4] = load_qk_frag(qb + (size_t)(t4 * 16 + r) * NQK, hh * 20 + 8 * g, g, true);
            kf[t4] = load_qk_frag(qb + (size_t)(t4 * 16 + r) * NQK, 300 + hh * 20 + 8 * g, g, true);
        }
        short8 vf[2][2];
        #pragma unroll
        for (int nt = 0; nt < 2; ++nt) {
            int vj = nt * 16 + r;
            #pragma unroll
            for (int ks = 0; ks < 2; ++ks) {
                if (vj < 20)
                    vf[nt][ks] = *(const short8*)&vt[(((size_t)b * 15 + hh) * 20 + vj) * 64 + ks * 32 + 8 * g];
                else
                    vf[nt][ks] = (short8){0,0,0,0,0,0,0,0};
            }
        }

        f32x4 s[4][4];
        #pragma unroll
        for (int qt = 0; qt < 4; ++qt)
            #pragma unroll
            for (int kt = 0; kt < 4; ++kt) {
                f32x4 z = {0.f, 0.f, 0.f, 0.f};
                s[qt][kt] = __builtin_amdgcn_mfma_f32_16x16x32_bf16(kf[kt], qf[qt], z, 0, 0, 0);
            }

        float mx[4], sm[4];
        #pragma unroll
        for (int qt = 0; qt < 4; ++qt) {
            float m = -1e30f;
            #pragma unroll
            for (int kt = 0; kt < 4; ++kt)
                #pragma unroll
                for (int j = 0; j < 4; ++j) {
                    int col = kt * 16 + 4 * g + j;
                    float v = (col < 50) ? s[qt][kt][j] * SCALE : -1e30f;
                    s[qt][kt][j] = v;
                    m = fmaxf(m, v);
                }
            m = fmaxf(m, __shfl_xor(m, 16, 64));
            m = fmaxf(m, __shfl_xor(m, 32, 64));
            mx[qt] = m;
            float sum = 0.f;
            #pragma unroll
            for (int kt = 0; kt < 4; ++kt)
                #pragma unroll
                for (int j = 0; j < 4; ++j) {
                    float e = __expf(s[qt][kt][j] - m);
                    s[qt][kt][j] = e;
                    sum += e;
                }
            sum += __shfl_xor(sum, 16, 64);
            sum += __shfl_xor(sum, 32, 64);
            sm[qt] = 1.0f / sum;
        }

        #pragma unroll
        for (int qt = 0; qt < 4; ++qt) {
            float inv = sm[qt];
            #pragma unroll
            for (int kt = 0; kt < 4; ++kt) {
                unsigned w0 = pack2bf(s[qt][kt][0] * inv, s[qt][kt][1] * inv);
                unsigned w1 = pack2bf(s[qt][kt][2] * inv, s[qt][kt][3] * inv);
                ushort* dst = pw + (qt * 16 + r) * 68 + kt * 16 + 4 * g;
                *(unsigned*)dst = w0;
                *(unsigned*)(dst + 2) = w1;
            }
        }
        asm volatile("s_waitcnt lgkmcnt(0)");
        __builtin_amdgcn_sched_barrier(0);

        #pragma unroll
        for (int lt = 0; lt < 4; ++lt) {
            short8 pf0 = *(const short8*)(pw + (lt * 16 + r) * 68 + 8 * g);
            short8 pf1 = *(const short8*)(pw + (lt * 16 + r) * 68 + 32 + 8 * g);
            int l = lt * 16 + r;
            #pragma unroll
            for (int nt = 0; nt < 2; ++nt) {
                f32x4 c = {0.f, 0.f, 0.f, 0.f};
                c = __builtin_amdgcn_mfma_f32_16x16x32_bf16(vf[nt][0], pf0, c, 0, 0, 0);
                c = __builtin_amdgcn_mfma_f32_16x16x32_bf16(vf[nt][1], pf1, c, 0, 0, 0);
                int vjb = nt * 16 + 4 * g;
                if (l < 50 && vjb < 17) {
                    unsigned w0 = pack2bf(c[0], c[1]);
                    unsigned w1 = pack2bf(c[2], c[3]);
                    ushort* d = ctx + ((size_t)b * 64 + l) * CTS + hh * 20 + vjb;
                    *(unsigned*)d = w0;
                    *(unsigned*)(d + 2) = w1;
                }
            }
        }
    }
}

// ---------- K4b: user pooling ----------
__global__ __launch_bounds__(256, 2)
void pool50(const ushort* __restrict__ ctx,   // [128][64][320]
            const ushort* __restrict__ wt_wp, // [208][320]
            const float* __restrict__ bp, const float* __restrict__ qv,
            float* __restrict__ user_rep)     // [128][300]
{
    __shared__ ushort Bt[2][208 * 40];
    __shared__ float  logit[128];
    __shared__ float  aw[128];

    const int tid  = threadIdx.x;
    const int wave = tid >> 6;
    const int lane = tid & 63;
    const int r = lane & 15, g = lane >> 4;

    const ushort* cbase = ctx + (size_t)blockIdx.x * 2 * 64 * CTS;

    auto stageB = [&](int ks, int buf) {
        for (int i = tid; i < 832; i += 256) {
            int n = i >> 2, kk = (i & 3) * 8;
            *(short8*)&Bt[buf][n * 40 + kk] = *(const short8*)&wt_wp[(size_t)n * KP + ks * 32 + kk];
        }
    };

    float bpr[13], qvr[13];
    #pragma unroll
    for (int nf = 0; nf < 13; ++nf) {
        int col = nf * 16 + r;
        bpr[nf] = (col < 200) ? bp[col] : 0.f;
        qvr[nf] = (col < 200) ? qv[col] : 0.f;
    }

    f32x4 acc[2][13];
    #pragma unroll
    for (int mf = 0; mf < 2; ++mf)
        #pragma unroll
        for (int nf = 0; nf < 13; ++nf)
            acc[mf][nf] = (f32x4){0.f, 0.f, 0.f, 0.f};

    stageB(0, 0);
    __syncthreads();
    int buf = 0;
    for (int ks = 0; ks < 10; ++ks) {
        if (ks < 9) stageB(ks + 1, buf ^ 1);
        short8 af[2];
        #pragma unroll
        for (int mf = 0; mf < 2; ++mf)
            af[mf] = *(const short8*)&cbase[(size_t)(wave * 32 + mf * 16 + r) * CTS + ks * 32 + 8 * g];
        #pragma unroll
        for (int mf = 0; mf < 2; ++mf)
            #pragma unroll
            for (int nf = 0; nf < 13; ++nf) {
                short8 bf = *(const short8*)&Bt[buf][(nf * 16 + r) * 40 + 8 * g];
                acc[mf][nf] = __builtin_amdgcn_mfma_f32_16x16x32_bf16(af[mf], bf, acc[mf][nf], 0, 0, 0);
            }
        __syncthreads();
        buf ^= 1;
    }

    #pragma unroll
    for (int mf = 0; mf < 2; ++mf) {
        #pragma unroll
        for (int j = 0; j < 4; ++j) {
            float s = 0.f;
            #pragma unroll
            for (int nf = 0; nf < 13; ++nf)
                s += tanhf(acc[mf][nf][j] + bpr[nf]) * qvr[nf];
            s += __shfl_xor(s, 1, 64);
            s += __shfl_xor(s, 2, 64);
            s += __shfl_xor(s, 4, 64);
            s += __shfl_xor(s, 8, 64);
            if (r == 0) logit[wave * 32 + mf * 16 + 4 * g + j] = s;
        }
    }
    __syncthreads();

    if (wave < 2) {
        float x = (lane < 50) ? logit[wave * 64 + lane] : -1e30f;
        float mx = x;
        #pragma unroll
        for (int off = 1; off < 64; off <<= 1) mx = fmaxf(mx, __shfl_xor(mx, off, 64));
        float e = (lane < 50) ? __expf(x - mx) : 0.f;
        float sm = e;
        #pragma unroll
        for (int off = 1; off < 64; off <<= 1) sm += __shfl_xor(sm, off, 64);
        aw[wave * 64 + lane] = e / sm;
    }
    __syncthreads();

    for (int idx = tid; idx < 2 * 300; idx += 256) {
        int inst = idx / 300, c = idx - inst * 300;
        const ushort* crow = cbase + (size_t)inst * 64 * CTS + c;
        float o = 0.f;
        #pragma unroll
        for (int l = 0; l < 50; ++l)
            o = fmaf(aw[inst * 64 + l], bf2f(crow[(size_t)l * CTS]), o);
        int b = blockIdx.x * 2 + inst;
        user_rep[(size_t)b * 300 + c] = o;
    }
}

// ---------- final scoring ----------
__global__ __launch_bounds__(320)
void score_kernel(const float* __restrict__ user_rep, const float* __restrict__ cand_enc,
                  float* __restrict__ out)
{
    __shared__ float sc[NCAND];
    int b = blockIdx.x;
    int w = threadIdx.x >> 6;
    int lane = threadIdx.x & 63;
    float partial = 0.f;
    for (int d = lane; d < 300; d += 64)
        partial = fmaf(user_rep[b * 300 + d], cand_enc[((size_t)b * NCAND + w) * 300 + d], partial);
    for (int off = 32; off > 0; off >>= 1)
        partial += __shfl_down(partial, off, 64);
    if (lane == 0) sc[w] = partial;
    __syncthreads();
    if (threadIdx.x == 0) {
        float mx = -1e30f;
        for (int c = 0; c < NCAND; ++c) mx = fmaxf(mx, sc[c]);
        float s = 0.f; float e[NCAND];
        for (int c = 0; c < NCAND; ++c) { e[c] = __expf(sc[c] - mx); s += e[c]; }
        float inv = 1.0f / s;
        for (int c = 0; c < NCAND; ++c) out[b * NCAND + c] = e[c] * inv;
    }
}

extern "C" void kernel_launch(void* const* d_in, const int* in_sizes, int n_in,
                              void* d_out, int out_size, void* d_ws, size_t ws_size,
                              hipStream_t stream) {
    const int*   news_input = (const int*)d_in[0];
    const int*   candidates = (const int*)d_in[1];
    const float* emb        = (const float*)d_in[2];
    const float* his_Wq  = (const float*)d_in[3];
    const float* his_Wk  = (const float*)d_in[4];
    const float* his_Wv  = (const float*)d_in[5];
    const float* his_Wp  = (const float*)d_in[6];
    const float* his_bp  = (const float*)d_in[7];
    const float* his_qv  = (const float*)d_in[8];
    const float* cand_Wq = (const float*)d_in[9];
    const float* cand_Wk = (const float*)d_in[10];
    const float* cand_Wv = (const float*)d_in[11];
    const float* cand_Wp = (const float*)d_in[12];
    const float* cand_bp = (const float*)d_in[13];
    const float* cand_qv = (const float*)d_in[14];
    const float* usr_Wq  = (const float*)d_in[15];
    const float* usr_Wk  = (const float*)d_in[16];
    const float* usr_Wv  = (const float*)d_in[17];
    const float* usr_Wp  = (const float*)d_in[18];
    const float* usr_bp  = (const float*)d_in[19];
    const float* usr_qv  = (const float*)d_in[20];
    float* out = (float*)d_out;

    char* ws = (char*)d_ws;
    ushort* emb_bf      = (ushort*)ws;            ws += (size_t)VOCAB * KP * 2;
    ushort* news_enc_bf = (ushort*)ws;            ws += (size_t)BATCH * NHIS * KP * 2;
    float* cand_enc = (float*)ws;                 ws += (size_t)BATCH * NCAND * 300 * 4;
    float* user_rep = (float*)ws;                 ws += (size_t)BATCH * 300 * 4;
    ushort* his_qkvT  = (ushort*)ws;              ws += (size_t)NHIS * NQKV * KP * 2;
    ushort* his_wpT   = (ushort*)ws;              ws += (size_t)NHIS * NWP  * KP * 2;
    ushort* cand_qkvT = (ushort*)ws;              ws += (size_t)NCAND * NQKV * KP * 2;
    ushort* cand_wpT  = (ushort*)ws;              ws += (size_t)NCAND * NWP  * KP * 2;
    ushort* usr_qkvT  = (ushort*)ws;              ws += (size_t)NQKV * KP * 2;
    ushort* usr_wpT   = (ushort*)ws;              ws += (size_t)NWP  * KP * 2;

    size_t used = (size_t)(ws - (char*)d_ws);
    size_t avail = (ws_size > used) ? (ws_size - used) : 0;
    size_t qk_pp  = (size_t)3840 * NQK * 2;
    size_t vt_pp  = (size_t)BATCH * 15 * 640 * 2;
    size_t per_p  = qk_pp + vt_pp;
    int CP = (int)(avail / per_p);
    if (CP > 50) CP = 50;
    if (CP < 3) CP = 3;   // user overlay (~16 MB) needs >= 3*per_p

    ushort* qk_ws  = (ushort*)ws;
    ushort* vt_ws  = qk_ws + (size_t)CP * 3840 * NQK;

    ushort* qk_u  = qk_ws;                                // [6400][640]
    ushort* vt_u  = qk_u + (size_t)6400 * NQK;            // [128][15][20][64]
    ushort* ctx_u = vt_u + (size_t)BATCH * 15 * 20 * 64;  // [128][64][320]

    auto blocks = [](size_t total) { return (int)((total + 255) / 256); };
    auto qkv_grid = [](int npmt) { return ((npmt + 7) / 8) * 64; };

    hipMemsetAsync(news_enc_bf, 0, (size_t)BATCH * NHIS * KP * 2, stream);
    prep_emb<<<blocks((size_t)VOCAB * (KP / 8)), 256, 0, stream>>>(emb, emb_bf);
    prep_qkv<<<blocks((size_t)NHIS  * NQKV * KP), 256, 0, stream>>>(his_Wq,  his_Wk,  his_Wv,  his_qkvT,  NHIS);
    prep_qkv<<<blocks((size_t)NCAND * NQKV * KP), 256, 0, stream>>>(cand_Wq, cand_Wk, cand_Wv, cand_qkvT, NCAND);
    prep_qkv<<<blocks((size_t)1     * NQKV * KP), 256, 0, stream>>>(usr_Wq,  usr_Wk,  usr_Wv,  usr_qkvT,  1);
    prep_wp <<<blocks((size_t)NHIS  * NWP  * KP), 256, 0, stream>>>(his_Wp,  his_wpT,  NHIS);
    prep_wp <<<blocks((size_t)NCAND * NWP  * KP), 256, 0, stream>>>(cand_Wp, cand_wpT, NCAND);
    prep_wp <<<blocks((size_t)1     * NWP  * KP), 256, 0, stream>>>(usr_Wp,  usr_wpT,  1);

    for (int p0 = 0; p0 < NHIS; p0 += CP) {
        int cp = (NHIS - p0 < CP) ? (NHIS - p0) : CP;
        int npmt = cp * 30;
        qkv_gemm<30, true><<<qkv_grid(npmt), 256, 0, stream>>>(emb_bf, news_input, his_qkvT,
                                                               qk_ws, vt_ws, p0, NHIS, npmt);
        attn_pool30<true><<<cp * BATCH, 256, 0, stream>>>(qk_ws, vt_ws, his_wpT, his_bp, his_qv,
                                                          nullptr, news_enc_bf, p0, NHIS);
    }
    {
        int npmt = NCAND * 30;
        qkv_gemm<30, true><<<qkv_grid(npmt), 256, 0, stream>>>(emb_bf, candidates, cand_qkvT,
                                                               qk_ws, vt_ws, 0, NCAND, npmt);
        attn_pool30<false><<<NCAND * BATCH, 256, 0, stream>>>(qk_ws, vt_ws, cand_wpT, cand_bp, cand_qv,
                                                              cand_enc, nullptr, 0, NCAND);
    }

    // user encoder
    hipMemsetAsync(vt_u, 0, (size_t)BATCH * 15 * 20 * 64 * 2, stream);
    qkv_gemm<50, false><<<qkv_grid(50), 256, 0, stream>>>(news_enc_bf, nullptr, usr_qkvT,
                                                          qk_u, vt_u, 0, 1, 50);
    attn50<<<BATCH, 512, 0, stream>>>(qk_u, vt_u, ctx_u);
    pool50<<<64, 256, 0, stream>>>(ctx_u, usr_wpT, usr_bp, usr_qv, user_rep);

    score_kernel<<<BATCH, 320, 0, stream>>>(user_rep, cand_enc, out);
}